// Round 1
// baseline (307.175 us; speedup 1.0000x reference)
//
#include <hip/hip_runtime.h>
#include <stdint.h>

// GatingLayer, fused single-kernel version (R4).
// logits = x[16384,3072] . W[8,3072]^T + b[8]; softmax(8); top-2 (stable,
// lowest-index tie-break); softmax over the selected 2.
// d_out = values (fp32 x 32768) ++ indices-as-float (x 32768).
//
// R4 theory: previous 286 us = ~240 us of 768-MiB workspace-poison fills
// (the top-5 rocprof dispatches, 84% HBM peak each) + ~45 us of kernels.
// This version uses NO workspace, NO LDS, NO barriers: one kernel computes
// the full-D dot product per token in registers, reads W (96 KB, L1/L2-hot)
// directly from global, butterfly-reduces partial sums across lanes, and
// does softmax/top-2/renorm in the epilogue.
//
// Lane map: wave owns 4 tokens. lane = sl*4 + tg; tg = token-in-wave [0,4),
// sl = d-slice [0,16). Stage = 64 floats of d (each sl covers 4 floats).
// 48 stages; register double-buffer 4 stages deep (xa/xb ping-pong).
// Per wave-instruction x-load: 4 tokens x 256 B contiguous -> 8 full lines,
// coalesced. W loads broadcast across the 4 tg lanes per sl group.

#define NTOK   16384
#define DMODEL 3072
#define NEXP   8
#define TPB    256                 // 4 waves
#define TOKB   16                  // tokens per block (4 waves x 4 tokens)
#define NST    48                  // stages of 64 floats: 48*64 = 3072
#define NSS    12                  // super-stages of 4 stages

__global__ __launch_bounds__(TPB) void gate_fused_kernel(
    const float* __restrict__ x, const float* __restrict__ W,
    const float* __restrict__ bias, float* __restrict__ out) {
  const int tid = threadIdx.x;
  const int wv = tid >> 6;
  const int lane = tid & 63;
  const int tg = lane & 3;         // token-in-wave
  const int sl = lane >> 2;        // d-slice [0,16)
  const int tok = blockIdx.x * TOKB + wv * 4 + tg;

  const float* px = x + (size_t)tok * DMODEL + sl * 4;
  const float* pw[NEXP];
#pragma unroll
  for (int e = 0; e < NEXP; ++e) pw[e] = W + (size_t)e * DMODEL + sl * 4;

  float acc[NEXP];
#pragma unroll
  for (int e = 0; e < NEXP; ++e) acc[e] = 0.f;

  float4 xa[4], xb[4];
#pragma unroll
  for (int k = 0; k < 4; ++k) xa[k] = *(const float4*)(px + k * 64);

#pragma unroll 1
  for (int ss = 0; ss < NSS; ss += 2) {
    // Prefetch super-stage ss+1 (register dbuf; compiler emits precise vmcnt).
#pragma unroll
    for (int k = 0; k < 4; ++k)
      xb[k] = *(const float4*)(px + ((ss + 1) * 4 + k) * 64);

    // Compute super-stage ss from xa.
#pragma unroll
    for (int k = 0; k < 4; ++k) {
      const int s = ss * 4 + k;
      float4 w4[NEXP];
#pragma unroll
      for (int e = 0; e < NEXP; ++e)
        w4[e] = *(const float4*)(pw[e] + s * 64);
      const float4 xv = xa[k];
#pragma unroll
      for (int e = 0; e < NEXP; ++e)
        acc[e] = fmaf(xv.x, w4[e].x,
                 fmaf(xv.y, w4[e].y,
                 fmaf(xv.z, w4[e].z,
                 fmaf(xv.w, w4[e].w, acc[e]))));
    }

    // Prefetch super-stage ss+2.
    if (ss + 2 < NSS) {
#pragma unroll
      for (int k = 0; k < 4; ++k)
        xa[k] = *(const float4*)(px + ((ss + 2) * 4 + k) * 64);
    }

    // Compute super-stage ss+1 from xb.
#pragma unroll
    for (int k = 0; k < 4; ++k) {
      const int s = (ss + 1) * 4 + k;
      float4 w4[NEXP];
#pragma unroll
      for (int e = 0; e < NEXP; ++e)
        w4[e] = *(const float4*)(pw[e] + s * 64);
      const float4 xv = xb[k];
#pragma unroll
      for (int e = 0; e < NEXP; ++e)
        acc[e] = fmaf(xv.x, w4[e].x,
                 fmaf(xv.y, w4[e].y,
                 fmaf(xv.z, w4[e].z,
                 fmaf(xv.w, w4[e].w, acc[e]))));
    }
  }

  // Reduce partial sums over the 16 d-slices: lane bits 2..5 butterfly.
#pragma unroll
  for (int e = 0; e < NEXP; ++e) {
    float v = acc[e];
    v += __shfl_xor(v, 4, 64);
    v += __shfl_xor(v, 8, 64);
    v += __shfl_xor(v, 16, 64);
    v += __shfl_xor(v, 32, 64);
    acc[e] = v;
  }

  // Epilogue: every lane redundantly computes its token tg's result
  // (uniform, no divergence); lanes 0..3 (sl==0) write.
  const float4 b0 = *(const float4*)bias;
  const float4 b1 = *(const float4*)(bias + 4);
  float l[NEXP];
  l[0] = acc[0] + b0.x; l[1] = acc[1] + b0.y;
  l[2] = acc[2] + b0.z; l[3] = acc[3] + b0.w;
  l[4] = acc[4] + b1.x; l[5] = acc[5] + b1.y;
  l[6] = acc[6] + b1.z; l[7] = acc[7] + b1.w;

  float m = l[0];
#pragma unroll
  for (int e = 1; e < NEXP; ++e) m = fmaxf(m, l[e]);

  float p8[NEXP];
  float ssum = 0.f;
#pragma unroll
  for (int e = 0; e < NEXP; ++e) {
    p8[e] = expf(l[e] - m);
    ssum += p8[e];
  }
  const float inv = 1.f / ssum;
#pragma unroll
  for (int e = 0; e < NEXP; ++e) p8[e] *= inv;

  // top-2, first-occurrence on ties (matches jax.lax.top_k stable order).
  int i1 = 0;
  float v1 = p8[0];
#pragma unroll
  for (int e = 1; e < NEXP; ++e) {
    if (p8[e] > v1) { v1 = p8[e]; i1 = e; }
  }
  int i2 = -1;
  float v2 = -1.f;
#pragma unroll
  for (int e = 0; e < NEXP; ++e) {
    if (e == i1) continue;
    if (p8[e] > v2) { v2 = p8[e]; i2 = e; }
  }

  // Second softmax over the two selected probabilities (v1 >= v2).
  const float e2 = expf(v2 - v1);
  const float r = 1.f / (1.f + e2);

  if (lane < 4) {  // lane == tg, one writer per token
    *(float2*)(out + (size_t)tok * 2) = make_float2(r, e2 * r);
    *(float2*)(out + 2 * NTOK + (size_t)tok * 2) =
        make_float2((float)i1, (float)i2);
  }
}

extern "C" void kernel_launch(void* const* d_in, const int* in_sizes, int n_in,
                              void* d_out, int out_size, void* d_ws,
                              size_t ws_size, hipStream_t stream) {
  const float* x = (const float*)d_in[0];
  const float* W = (const float*)d_in[1];
  const float* b = (const float*)d_in[2];
  float* out = (float*)d_out;
  (void)d_ws; (void)ws_size;  // workspace intentionally unused (R4 theory)

  gate_fused_kernel<<<dim3(NTOK / TOKB), TPB, 0, stream>>>(x, W, b, out);
}

// Round 2
// 293.096 us; speedup vs baseline: 1.0480x; 1.0480x over previous
//
#include <hip/hip_runtime.h>
#include <stdint.h>

// GatingLayer fused kernel, R5.
// logits = x[16384,3072] . W[8,3072]^T + b[8]; softmax(8); top-2 (stable,
// lowest-index tie-break); softmax over the selected 2.
// d_out = values (fp32 x 32768) ++ indices-as-float (x 32768).
//
// R5 theory (R4 post-mortem): R4's W loads were GLOBAL inside the K-loop.
// vmcnt retires in issue order, so consuming W (issued after the x HBM
// prefetch) forced a wait that drained the x prefetch -> every stage
// serialized behind ~900cy HBM latency (kernel ~67us vs ~39 for R3's
// LDS-W design). Fix: W lives in LDS (lgkm domain, independent of the x
// vmcnt domain), double-buffered in 8 KB chunks, reg-staged with the W
// global loads issued BEFORE the x prefetch so their vmcnt wait never
// drains x. Fused epilogue keeps the no-workspace / single-launch win
// (~7us vs R3's partials+second kernel). The ~238us of harness workspace
// poison fills (2 x 768 MiB at ~6.7 TB/s) is a structural floor.
//
// Lane map: lane = sl*2 + tg; sl in [0,32) = d-slice (4 floats of each
// 128-float stage), tg in [0,2). Wave owns 8 tokens: 4 streams x 2 tg.
// acc[4][8]. Butterfly over lane bits 1..5 reduces d-slices; lanes 0..7
// write (one per token). Grid 512 blocks = 2 blocks/CU = 8 waves/CU.

#define NTOK   16384
#define DMODEL 3072
#define NEXP   8
#define TPB    256             // 4 waves
#define TOKW   8               // tokens per wave
#define TOKB   32              // tokens per block
#define CHF    256             // floats per expert per chunk (2 stages x 128)
#define NCH    (DMODEL / CHF)  // 12 chunks
#define LDSF   (NEXP * CHF)    // 2048 floats = 8 KB per buffer

#define GATE_COMPUTE(SW, XR)                                          \
  {                                                                   \
    _Pragma("unroll")                                                 \
    for (int st = 0; st < 2; ++st) {                                  \
      float4 w4[NEXP];                                                \
      _Pragma("unroll")                                               \
      for (int e = 0; e < NEXP; ++e)                                  \
        w4[e] = *(const float4*)&SW[e * CHF + st * 128 + sl * 4];     \
      _Pragma("unroll")                                               \
      for (int p = 0; p < 4; ++p) {                                   \
        const float4 xv = XR[st * 4 + p];                             \
        _Pragma("unroll")                                             \
        for (int e = 0; e < NEXP; ++e)                                \
          acc[p][e] = fmaf(xv.x, w4[e].x,                             \
                      fmaf(xv.y, w4[e].y,                             \
                      fmaf(xv.z, w4[e].z,                             \
                      fmaf(xv.w, w4[e].w, acc[p][e]))));              \
      }                                                               \
    }                                                                 \
  }

__global__ __launch_bounds__(TPB) void gate_fused2(
    const float* __restrict__ x, const float* __restrict__ W,
    const float* __restrict__ bias, float* __restrict__ out) {
  __shared__ float swA[LDSF];
  __shared__ float swB[LDSF];

  const int tid  = threadIdx.x;
  const int wv   = tid >> 6;
  const int lane = tid & 63;
  const int tg   = lane & 1;
  const int sl   = lane >> 1;                    // d-slice [0,32)
  const int tokBase = blockIdx.x * TOKB + wv * TOKW;

  // x: 4 token streams per lane, this lane's 16B d-slice.
  const float* px[4];
#pragma unroll
  for (int p = 0; p < 4; ++p)
    px[p] = x + (size_t)(tokBase + p * 2 + tg) * DMODEL + sl * 4;

  // W staging map: thread stages float4 f=tid (expert wv) and f=256+tid
  // (expert 4+wv); LDS dest is linear in f -> sw[f*4].
  const float* pw0 = W + (size_t)wv * DMODEL + (tid & 63) * 4;
  const float* pw1 = W + (size_t)(4 + wv) * DMODEL + (tid & 63) * 4;
  const int d0 = tid * 4;
  const int d1 = 1024 + tid * 4;

  float acc[4][NEXP];
#pragma unroll
  for (int p = 0; p < 4; ++p)
#pragma unroll
    for (int e = 0; e < NEXP; ++e) acc[p][e] = 0.f;

  // ---- prologue: stage chunk 0 (W regs first, then x) ----
  float4 w0 = *(const float4*)(pw0);
  float4 w1 = *(const float4*)(pw1);
  float4 xa[8], xb[8];
#pragma unroll
  for (int st = 0; st < 2; ++st)
#pragma unroll
    for (int p = 0; p < 4; ++p)
      xa[st * 4 + p] = *(const float4*)(px[p] + st * 128);
  *(float4*)&swA[d0] = w0;
  *(float4*)&swA[d1] = w1;
  __syncthreads();

#pragma unroll 1
  for (int cc = 0; cc < NCH; cc += 2) {
    // Stage chunk cc+1 -> B. W loads issued BEFORE x prefetch: waiting for
    // the W regs (older in vmcnt order) never drains the x loads.
    w0 = *(const float4*)(pw0 + (cc + 1) * CHF);
    w1 = *(const float4*)(pw1 + (cc + 1) * CHF);
#pragma unroll
    for (int st = 0; st < 2; ++st)
#pragma unroll
      for (int p = 0; p < 4; ++p)
        xb[st * 4 + p] =
            *(const float4*)(px[p] + ((cc + 1) * 2 + st) * 128);

    GATE_COMPUTE(swA, xa);          // lgkm-domain W reads; x from registers

    *(float4*)&swB[d0] = w0;        // safe: all waves' B-reads ended before
    *(float4*)&swB[d1] = w1;        // the previous barrier
    __syncthreads();

    if (cc + 2 < NCH) {             // stage chunk cc+2 -> A
      w0 = *(const float4*)(pw0 + (cc + 2) * CHF);
      w1 = *(const float4*)(pw1 + (cc + 2) * CHF);
#pragma unroll
      for (int st = 0; st < 2; ++st)
#pragma unroll
        for (int p = 0; p < 4; ++p)
          xa[st * 4 + p] =
              *(const float4*)(px[p] + ((cc + 2) * 2 + st) * 128);
    }

    GATE_COMPUTE(swB, xb);

    if (cc + 2 < NCH) {
      *(float4*)&swA[d0] = w0;
      *(float4*)&swA[d1] = w1;
    }
    __syncthreads();
  }

  // Reduce over the 32 d-slices: butterfly on lane bits 1..5.
#pragma unroll
  for (int p = 0; p < 4; ++p)
#pragma unroll
    for (int e = 0; e < NEXP; ++e) {
      float v = acc[p][e];
      v += __shfl_xor(v, 2, 64);
      v += __shfl_xor(v, 4, 64);
      v += __shfl_xor(v, 8, 64);
      v += __shfl_xor(v, 16, 64);
      v += __shfl_xor(v, 32, 64);
      acc[p][e] = v;
    }

  // Epilogue: lanes 0..7 each own one token (lane = p*2+tg <=> sl==p).
  const float4 b0 = *(const float4*)bias;
  const float4 b1 = *(const float4*)(bias + 4);

#pragma unroll
  for (int p = 0; p < 4; ++p) {
    if (sl == p) {                   // compile-time acc index, divergent write
      float l[NEXP];
      l[0] = acc[p][0] + b0.x; l[1] = acc[p][1] + b0.y;
      l[2] = acc[p][2] + b0.z; l[3] = acc[p][3] + b0.w;
      l[4] = acc[p][4] + b1.x; l[5] = acc[p][5] + b1.y;
      l[6] = acc[p][6] + b1.z; l[7] = acc[p][7] + b1.w;

      float m = l[0];
#pragma unroll
      for (int e = 1; e < NEXP; ++e) m = fmaxf(m, l[e]);

      float p8[NEXP];
      float ssum = 0.f;
#pragma unroll
      for (int e = 0; e < NEXP; ++e) {
        p8[e] = expf(l[e] - m);
        ssum += p8[e];
      }
      const float inv = 1.f / ssum;
#pragma unroll
      for (int e = 0; e < NEXP; ++e) p8[e] *= inv;

      // top-2, first-occurrence on ties (matches jax.lax.top_k order).
      int i1 = 0;
      float v1 = p8[0];
#pragma unroll
      for (int e = 1; e < NEXP; ++e) {
        if (p8[e] > v1) { v1 = p8[e]; i1 = e; }
      }
      int i2 = -1;
      float v2 = -1.f;
#pragma unroll
      for (int e = 0; e < NEXP; ++e) {
        if (e == i1) continue;
        if (p8[e] > v2) { v2 = p8[e]; i2 = e; }
      }

      const float e2 = expf(v2 - v1);  // v1 >= v2
      const float r = 1.f / (1.f + e2);

      const int tok = tokBase + p * 2 + tg;
      *(float2*)(out + (size_t)tok * 2) = make_float2(r, e2 * r);
      *(float2*)(out + 2 * NTOK + (size_t)tok * 2) =
          make_float2((float)i1, (float)i2);
    }
  }
}

extern "C" void kernel_launch(void* const* d_in, const int* in_sizes, int n_in,
                              void* d_out, int out_size, void* d_ws,
                              size_t ws_size, hipStream_t stream) {
  const float* x = (const float*)d_in[0];
  const float* W = (const float*)d_in[1];
  const float* b = (const float*)d_in[2];
  float* out = (float*)d_out;
  (void)d_ws; (void)ws_size;  // unused; poison fills are unconditional anyway

  gate_fused2<<<dim3(NTOK / TOKB), TPB, 0, stream>>>(x, W, b, out);
}

// Round 3
// 282.961 us; speedup vs baseline: 1.0856x; 1.0358x over previous
//
#include <hip/hip_runtime.h>
#include <stdint.h>

// GatingLayer fused kernel, R6.
// logits = x[16384,3072] . W[8,3072]^T + b[8]; softmax(8); top-2 (stable,
// lowest-index tie-break); softmax over the selected 2.
// d_out = values (fp32 x 32768) ++ indices-as-float (x 32768).
//
// R6 design: ZERO barriers, ZERO LDS, ZERO workspace, ONE kernel.
// R4 failed because W(s) was consumed in the iteration it was issued,
// after the x(s+1) prefetch -> the W wait drained the x prefetch (vmcnt
// retires in issue order). R5 fixed W via LDS but paid 13 barriers/block
// (each = s_waitcnt vmcnt(0) + s_barrier -> drains x anyway). R6: W is
// register-double-buffered IN THE SAME PREFETCH CLUMP as x. compute(i)
// consumes only clump-i regs (older than all of clump i+1), so the
// compiler's per-register vmcnt wait leaves clump i+1 outstanding.
//
// Lane map: lane = sl*2 + tg. sl in [0,32) = d-slice of a 128-float
// stage; tg in [0,2) = expert half (tg=0 -> experts 0-3, tg=1 -> 4-7).
// Wave owns 8 tokens (streams p in [0,8)); both tg lanes of an sl pair
// read the SAME x float4 (coalesces to one line, no extra traffic);
// x wave-load = 512 B contiguous per token. acc[8][4] = 32 VGPRs.
// 24 stages of 128 d, ping-pong clumps {wa,xa}/{wb,xb}.
// Grid 512 x 256 thr = 32 tokens/block, 2 blocks/CU, 8 waves/CU.
//
// Epilogue: butterfly over sl (xor 2,4,8,16,32) reduces d; lane pair
// (p, p^1) exchanges expert halves for token p via one shfl_xor(1);
// lanes 0..7 each run softmax/top-2/renorm for their token and write.

#define NTOK   16384
#define DMODEL 3072
#define NEXP   8
#define TPB    256              // 4 waves
#define TOKW   8                // tokens per wave
#define TOKB   32               // tokens per block
#define STF    128              // floats of d per stage
#define NST    (DMODEL / STF)   // 24 stages

#define GATE_COMPUTE(WR, XR)                                          \
  {                                                                   \
    _Pragma("unroll")                                                 \
    for (int p = 0; p < TOKW; ++p) {                                  \
      const float4 xv = XR[p];                                        \
      _Pragma("unroll")                                               \
      for (int e = 0; e < 4; ++e)                                     \
        acc[p][e] = fmaf(xv.x, WR[e].x,                               \
                    fmaf(xv.y, WR[e].y,                               \
                    fmaf(xv.z, WR[e].z,                               \
                    fmaf(xv.w, WR[e].w, acc[p][e]))));                \
    }                                                                 \
  }

__global__ __launch_bounds__(TPB) void gate_fused3(
    const float* __restrict__ x, const float* __restrict__ W,
    const float* __restrict__ bias, float* __restrict__ out) {
  const int tid  = threadIdx.x;
  const int wv   = tid >> 6;
  const int lane = tid & 63;
  const int tg   = lane & 1;        // expert half
  const int sl   = lane >> 1;       // d-slice [0,32)
  const int tokBase = blockIdx.x * TOKB + wv * TOKW;

  // x: 8 token streams, this lane's 16B slice of each 128-float stage.
  const float* px[TOKW];
#pragma unroll
  for (int p = 0; p < TOKW; ++p)
    px[p] = x + (size_t)(tokBase + p) * DMODEL + sl * 4;

  // W: this lane's 4 experts (tg half), same 16B slice.
  const float* pw[4];
#pragma unroll
  for (int e = 0; e < 4; ++e)
    pw[e] = W + (size_t)(tg * 4 + e) * DMODEL + sl * 4;

  float acc[TOKW][4];
#pragma unroll
  for (int p = 0; p < TOKW; ++p)
#pragma unroll
    for (int e = 0; e < 4; ++e) acc[p][e] = 0.f;

  // ---- prologue: clump 0 (W + x together) ----
  float4 wa[4], wb[4], xa[TOKW], xb[TOKW];
#pragma unroll
  for (int e = 0; e < 4; ++e) wa[e] = *(const float4*)(pw[e]);
#pragma unroll
  for (int p = 0; p < TOKW; ++p) xa[p] = *(const float4*)(px[p]);

#pragma unroll 1
  for (int s = 0; s < NST; s += 2) {
    // prefetch clump s+1
#pragma unroll
    for (int e = 0; e < 4; ++e)
      wb[e] = *(const float4*)(pw[e] + (s + 1) * STF);
#pragma unroll
    for (int p = 0; p < TOKW; ++p)
      xb[p] = *(const float4*)(px[p] + (s + 1) * STF);

    GATE_COMPUTE(wa, xa);           // consumes clump s only

    if (s + 2 < NST) {              // prefetch clump s+2
#pragma unroll
      for (int e = 0; e < 4; ++e)
        wa[e] = *(const float4*)(pw[e] + (s + 2) * STF);
#pragma unroll
      for (int p = 0; p < TOKW; ++p)
        xa[p] = *(const float4*)(px[p] + (s + 2) * STF);
    }

    GATE_COMPUTE(wb, xb);           // consumes clump s+1 only
  }

  // ---- reduce d-slices: butterfly over lane bits 1..5 ----
#pragma unroll
  for (int p = 0; p < TOKW; ++p)
#pragma unroll
    for (int e = 0; e < 4; ++e) {
      float v = acc[p][e];
      v += __shfl_xor(v, 2, 64);
      v += __shfl_xor(v, 4, 64);
      v += __shfl_xor(v, 8, 64);
      v += __shfl_xor(v, 16, 64);
      v += __shfl_xor(v, 32, 64);
      acc[p][e] = v;
    }
  // Now all lanes with equal tg hold identical acc.

  // ---- cross-tg expert-half exchange (lane p <-> p^1 for token p) ----
  // own[e]  = acc[lane&7][e]        (this lane's token, its expert half)
  // send[e] = acc[(lane^1)&7][e]    (partner's token, this expert half)
  float own[4], send[4];
#pragma unroll
  for (int p = 0; p < TOKW; ++p) {
    const bool isown  = (lane & 7) == p;
    const bool issend = ((lane ^ 1) & 7) == p;
#pragma unroll
    for (int e = 0; e < 4; ++e) {
      if (isown)  own[e]  = acc[p][e];
      if (issend) send[e] = acc[p][e];
    }
  }
  float other[4];
#pragma unroll
  for (int e = 0; e < 4; ++e) other[e] = __shfl_xor(send[e], 1, 64);

  if (lane < TOKW) {                // lane p owns token tokBase + p
    const float4 b0 = *(const float4*)bias;
    const float4 b1 = *(const float4*)(bias + 4);

    float l[NEXP];
    if ((lane & 1) == 0) {          // own = experts 0-3, other = 4-7
      l[0] = own[0] + b0.x;   l[1] = own[1] + b0.y;
      l[2] = own[2] + b0.z;   l[3] = own[3] + b0.w;
      l[4] = other[0] + b1.x; l[5] = other[1] + b1.y;
      l[6] = other[2] + b1.z; l[7] = other[3] + b1.w;
    } else {                        // own = experts 4-7, other = 0-3
      l[0] = other[0] + b0.x; l[1] = other[1] + b0.y;
      l[2] = other[2] + b0.z; l[3] = other[3] + b0.w;
      l[4] = own[0] + b1.x;   l[5] = own[1] + b1.y;
      l[6] = own[2] + b1.z;   l[7] = own[3] + b1.w;
    }

    float m = l[0];
#pragma unroll
    for (int e = 1; e < NEXP; ++e) m = fmaxf(m, l[e]);

    float p8[NEXP];
    float ssum = 0.f;
#pragma unroll
    for (int e = 0; e < NEXP; ++e) {
      p8[e] = expf(l[e] - m);
      ssum += p8[e];
    }
    const float inv = 1.f / ssum;
#pragma unroll
    for (int e = 0; e < NEXP; ++e) p8[e] *= inv;

    // top-2, first-occurrence on ties (matches jax.lax.top_k order).
    int i1 = 0;
    float v1 = p8[0];
#pragma unroll
    for (int e = 1; e < NEXP; ++e) {
      if (p8[e] > v1) { v1 = p8[e]; i1 = e; }
    }
    int i2 = -1;
    float v2 = -1.f;
#pragma unroll
    for (int e = 0; e < NEXP; ++e) {
      if (e == i1) continue;
      if (p8[e] > v2) { v2 = p8[e]; i2 = e; }
    }

    const float e2 = expf(v2 - v1);  // v1 >= v2
    const float r = 1.f / (1.f + e2);

    const int tok = tokBase + lane;
    *(float2*)(out + (size_t)tok * 2) = make_float2(r, e2 * r);
    *(float2*)(out + 2 * NTOK + (size_t)tok * 2) =
        make_float2((float)i1, (float)i2);
  }
}

extern "C" void kernel_launch(void* const* d_in, const int* in_sizes, int n_in,
                              void* d_out, int out_size, void* d_ws,
                              size_t ws_size, hipStream_t stream) {
  const float* x = (const float*)d_in[0];
  const float* W = (const float*)d_in[1];
  const float* b = (const float*)d_in[2];
  float* out = (float*)d_out;
  (void)d_ws; (void)ws_size;  // unused; poison fills are unconditional

  gate_fused3<<<dim3(NTOK / TOKB), TPB, 0, stream>>>(x, W, b, out);
}

// Round 4
// 280.947 us; speedup vs baseline: 1.0934x; 1.0072x over previous
//
#include <hip/hip_runtime.h>
#include <stdint.h>

// GatingLayer fused kernel, R7.
// logits = x[16384,3072] . W[8,3072]^T + b[8]; softmax(8); top-2 (stable,
// lowest-index tie-break); softmax over the selected 2.
// d_out = values (fp32 x 32768) ++ indices-as-float (x 32768).
//
// R7 = R6 (zero barriers / zero LDS / zero workspace / register clump
// double-buffer) at HALF the per-wave state to double occupancy.
// R6 post-mortem: ~160 VGPR -> 2 waves/SIMD; clump lookahead (~512-1024
// wall cycles) ~= HBM latency (~900 cy), so waves stalled with too few
// co-resident waves to cover -> 4.5 TB/s (71% of achievable). R7: TOKW
// 8->4 cuts acc+buffers+pointers to ~100 VGPR; __launch_bounds__(256,4)
// pins <=128 VGPR -> 4 waves/SIMD, 16 waves/CU, grid 1024 = 4 blocks/CU.
//
// Lane map: lane = sl*2 + tg. sl in [0,32) = 16B d-slice of a 128-float
// stage; tg in [0,2) = expert half (tg=0 -> experts 0-3, else 4-7).
// Wave owns 4 tokens. Both tg lanes read the same x float4 (coalesces,
// no extra HBM traffic). acc[4][4] = 16 VGPRs. 24 stages of 128 d,
// ping-pong clumps {wa,xa}/{wb,xb}; compute(i) consumes only clump-i
// registers (older in vmcnt order than all of clump i+1), so the
// compiler's per-register vmcnt waits never drain the next prefetch.

#define NTOK   16384
#define DMODEL 3072
#define NEXP   8
#define TPB    256              // 4 waves
#define TOKW   4                // tokens per wave
#define TOKB   16               // tokens per block
#define STF    128              // floats of d per stage
#define NST    (DMODEL / STF)   // 24 stages

#define GATE_COMPUTE(WR, XR)                                          \
  {                                                                   \
    _Pragma("unroll")                                                 \
    for (int p = 0; p < TOKW; ++p) {                                  \
      const float4 xv = XR[p];                                        \
      _Pragma("unroll")                                               \
      for (int e = 0; e < 4; ++e)                                     \
        acc[p][e] = fmaf(xv.x, WR[e].x,                               \
                    fmaf(xv.y, WR[e].y,                               \
                    fmaf(xv.z, WR[e].z,                               \
                    fmaf(xv.w, WR[e].w, acc[p][e]))));                \
    }                                                                 \
  }

__global__ __launch_bounds__(TPB, 4) void gate_fused4(
    const float* __restrict__ x, const float* __restrict__ W,
    const float* __restrict__ bias, float* __restrict__ out) {
  const int tid  = threadIdx.x;
  const int wv   = tid >> 6;
  const int lane = tid & 63;
  const int tg   = lane & 1;        // expert half
  const int sl   = lane >> 1;       // d-slice [0,32)
  const int tokBase = blockIdx.x * TOKB + wv * TOKW;

  // x: 4 token streams, this lane's 16B slice of each 128-float stage.
  const float* px[TOKW];
#pragma unroll
  for (int p = 0; p < TOKW; ++p)
    px[p] = x + (size_t)(tokBase + p) * DMODEL + sl * 4;

  // W: this lane's 4 experts (tg half), same 16B slice.
  const float* pw[4];
#pragma unroll
  for (int e = 0; e < 4; ++e)
    pw[e] = W + (size_t)(tg * 4 + e) * DMODEL + sl * 4;

  float acc[TOKW][4];
#pragma unroll
  for (int p = 0; p < TOKW; ++p)
#pragma unroll
    for (int e = 0; e < 4; ++e) acc[p][e] = 0.f;

  // ---- prologue: clump 0 (W + x together) ----
  float4 wa[4], wb[4], xa[TOKW], xb[TOKW];
#pragma unroll
  for (int e = 0; e < 4; ++e) wa[e] = *(const float4*)(pw[e]);
#pragma unroll
  for (int p = 0; p < TOKW; ++p) xa[p] = *(const float4*)(px[p]);

#pragma unroll 1
  for (int s = 0; s < NST; s += 2) {
    // prefetch clump s+1
#pragma unroll
    for (int e = 0; e < 4; ++e)
      wb[e] = *(const float4*)(pw[e] + (s + 1) * STF);
#pragma unroll
    for (int p = 0; p < TOKW; ++p)
      xb[p] = *(const float4*)(px[p] + (s + 1) * STF);

    GATE_COMPUTE(wa, xa);           // consumes clump s only

    if (s + 2 < NST) {              // prefetch clump s+2
#pragma unroll
      for (int e = 0; e < 4; ++e)
        wa[e] = *(const float4*)(pw[e] + (s + 2) * STF);
#pragma unroll
      for (int p = 0; p < TOKW; ++p)
        xa[p] = *(const float4*)(px[p] + (s + 2) * STF);
    }

    GATE_COMPUTE(wb, xb);           // consumes clump s+1 only
  }

  // ---- reduce d-slices: butterfly over lane bits 1..5 ----
#pragma unroll
  for (int p = 0; p < TOKW; ++p)
#pragma unroll
    for (int e = 0; e < 4; ++e) {
      float v = acc[p][e];
      v += __shfl_xor(v, 2, 64);
      v += __shfl_xor(v, 4, 64);
      v += __shfl_xor(v, 8, 64);
      v += __shfl_xor(v, 16, 64);
      v += __shfl_xor(v, 32, 64);
      acc[p][e] = v;
    }
  // Now all lanes with equal tg hold identical acc (full-d sums).

  // ---- cross-tg expert-half exchange (lane p <-> p^1 for token p) ----
  // own[e]  = acc[lane&3][e]      (this lane's token, its expert half)
  // send[e] = acc[(lane^1)&3][e]  (partner's token, this expert half)
  float own[4], send[4];
#pragma unroll
  for (int p = 0; p < TOKW; ++p) {
    const bool isown  = (lane & 3) == p;
    const bool issend = ((lane ^ 1) & 3) == p;
#pragma unroll
    for (int e = 0; e < 4; ++e) {
      if (isown)  own[e]  = acc[p][e];
      if (issend) send[e] = acc[p][e];
    }
  }
  float other[4];
#pragma unroll
  for (int e = 0; e < 4; ++e) other[e] = __shfl_xor(send[e], 1, 64);

  if (lane < TOKW) {                // lane p owns token tokBase + p
    const float4 b0 = *(const float4*)bias;
    const float4 b1 = *(const float4*)(bias + 4);

    float l[NEXP];
    if ((lane & 1) == 0) {          // own = experts 0-3, other = 4-7
      l[0] = own[0] + b0.x;   l[1] = own[1] + b0.y;
      l[2] = own[2] + b0.z;   l[3] = own[3] + b0.w;
      l[4] = other[0] + b1.x; l[5] = other[1] + b1.y;
      l[6] = other[2] + b1.z; l[7] = other[3] + b1.w;
    } else {                        // own = experts 4-7, other = 0-3
      l[0] = other[0] + b0.x; l[1] = other[1] + b0.y;
      l[2] = other[2] + b0.z; l[3] = other[3] + b0.w;
      l[4] = own[0] + b1.x;   l[5] = own[1] + b1.y;
      l[6] = own[2] + b1.z;   l[7] = own[3] + b1.w;
    }

    float m = l[0];
#pragma unroll
    for (int e = 1; e < NEXP; ++e) m = fmaxf(m, l[e]);

    float p8[NEXP];
    float ssum = 0.f;
#pragma unroll
    for (int e = 0; e < NEXP; ++e) {
      p8[e] = expf(l[e] - m);
      ssum += p8[e];
    }
    const float inv = 1.f / ssum;
#pragma unroll
    for (int e = 0; e < NEXP; ++e) p8[e] *= inv;

    // top-2, first-occurrence on ties (matches jax.lax.top_k order).
    int i1 = 0;
    float v1 = p8[0];
#pragma unroll
    for (int e = 1; e < NEXP; ++e) {
      if (p8[e] > v1) { v1 = p8[e]; i1 = e; }
    }
    int i2 = -1;
    float v2 = -1.f;
#pragma unroll
    for (int e = 0; e < NEXP; ++e) {
      if (e == i1) continue;
      if (p8[e] > v2) { v2 = p8[e]; i2 = e; }
    }

    const float e2 = expf(v2 - v1);  // v1 >= v2
    const float r = 1.f / (1.f + e2);

    const int tok = tokBase + lane;
    *(float2*)(out + (size_t)tok * 2) = make_float2(r, e2 * r);
    *(float2*)(out + 2 * NTOK + (size_t)tok * 2) =
        make_float2((float)i1, (float)i2);
  }
}

extern "C" void kernel_launch(void* const* d_in, const int* in_sizes, int n_in,
                              void* d_out, int out_size, void* d_ws,
                              size_t ws_size, hipStream_t stream) {
  const float* x = (const float*)d_in[0];
  const float* W = (const float*)d_in[1];
  const float* b = (const float*)d_in[2];
  float* out = (float*)d_out;
  (void)d_ws; (void)ws_size;  // unused; poison fills are unconditional

  gate_fused4<<<dim3(NTOK / TOKB), TPB, 0, stream>>>(x, W, b, out);
}